// Round 1
// 5701.638 us; speedup vs baseline: 1.3247x; 1.3247x over previous
//
#include <hip/hip_runtime.h>
#include <stdint.h>

typedef unsigned short u16;
typedef unsigned int u32;
typedef unsigned long long u64;

#define Hdim 512
#define Ddim 300
#define Tlen 1024
#define VG 40000
#define VS 25000
#define NGTOT (Tlen * VG)          // 40,960,000
#define NTOT  (Tlen * (VG + VS))   // 66,560,000

// ---- workspace layout (in floats; u64 arrays occupy 2 floats/elem) ----
#define F_XZ   0
#define F_XR   (F_XZ + Tlen * Hdim)
#define F_X1   (F_XR + Tlen * Hdim)
#define F_H1X  (F_X1 + Tlen * Hdim)            // u64[(Tlen+1)*512]
#define F_H2X  (F_H1X + (Tlen + 1) * Hdim * 2) // u64[(Tlen+1)*512]
#define F_R1X  (F_H2X + (Tlen + 1) * Hdim * 2) // u64[Tlen*512]
#define F_R2X  (F_R1X + Tlen * Hdim * 2)       // u64[Tlen*512]
#define F_HBF  (F_R2X + Tlen * Hdim * 2)       // u16[1024*512]
#define F_WGBF (F_HBF + (Tlen * Hdim) / 2)     // u16[512*40000]
#define F_WSBF (F_WGBF + (Hdim * VG) / 2)      // u16[512*25000]
#define F_PG   (F_WSBF + (Hdim * VS) / 2)      // [1024][625]
#define F_PS   (F_PG + Tlen * 625)             // [1024][391]
#define F_LSE  (F_PS + Tlen * 391)             // [2048]

__device__ __forceinline__ u16 f2bf(float f) {
    u32 u = __float_as_uint(f);
    u += 0x7fffu + ((u >> 16) & 1u);
    return (u16)(u >> 16);
}
__device__ __forceinline__ float bf2f(u16 s) { return __uint_as_float(((u32)s) << 16); }
__device__ __forceinline__ float sigm(float x) { return 1.f / (1.f + __expf(-x)); }

// tagged u64 exchange: {tag(step) in high32, f32 payload in low32}
__device__ __forceinline__ u64 pk(u32 tag, float v) {
    return ((u64)tag << 32) | (u64)__float_as_uint(v);
}
__device__ __forceinline__ float upf(u64 x) { return __uint_as_float((u32)x); }
__device__ __forceinline__ u32 uptag(u64 x) { return (u32)(x >> 32); }
__device__ __forceinline__ u64 ld64(const u64* p) {
    return __hip_atomic_load(p, __ATOMIC_RELAXED, __HIP_MEMORY_SCOPE_AGENT);
}
__device__ __forceinline__ void st64(u64* p, u64 v) {
    __hip_atomic_store(p, v, __ATOMIC_RELAXED, __HIP_MEMORY_SCOPE_AGENT);
}
// per-thread tag spin: wait until *p carries tag tg, return payload word.
// No barrier in the loop: wave-level divergence gives the AND for free, and
// lanes that are done stop issuing poll loads (less coherence-point traffic).
__device__ __forceinline__ u64 spin64(const u64* p, u32 tg) {
    u64 a = ld64(p);
    while (uptag(a) != tg) { __builtin_amdgcn_s_sleep(1); a = ld64(p); }
    return a;
}

// ---------------- init: seed h1x[0], h2x[0] with tag=1, val=0 ----------------
__global__ void k_init(u64* h1x, u64* h2x) {
    int i = blockIdx.x * 256 + threadIdx.x;
    if (i < Hdim) { h1x[i] = pk(1u, 0.f); h2x[i] = pk(1u, 0.f); }
}

// ---------------- x-projections: x_emb @ {Wz1,Wr1,W1} ----------------
__launch_bounds__(256)
__global__ void k_xproj(const int* tokens, const float* X,
                        const float* Wz1, const float* Wr1, const float* W1,
                        float* xz, float* xr, float* x1) {
    int tid = threadIdx.x;
    int jj = tid & 63, tg = tid >> 6;
    int mat = blockIdx.y >> 3;
    int j0 = (blockIdx.y & 7) * 64;
    int t0 = blockIdx.x * 16 + tg * 4;
    const float* W = (mat == 0) ? Wz1 : (mat == 1 ? Wr1 : W1);
    float* out = (mat == 0) ? xz : (mat == 1 ? xr : x1);
    const float* xrow[4];
#pragma unroll
    for (int u = 0; u < 4; ++u) xrow[u] = X + (size_t)tokens[t0 + u] * Ddim;
    float acc[4] = {0.f, 0.f, 0.f, 0.f};
    for (int k = 0; k < Ddim; ++k) {
        float w = W[(size_t)k * Hdim + j0 + jj];
#pragma unroll
        for (int u = 0; u < 4; ++u) acc[u] += xrow[u][k] * w;
    }
#pragma unroll
    for (int u = 0; u < 4; ++u) out[(size_t)(t0 + u) * Hdim + j0 + jj] = acc[u];
}

// ---------------- vocab weight fp32 -> bf16 ----------------
__global__ void k_wconv(const float* Wg, const float* Ws, u16* wgbf, u16* wsbf) {
    const int n4g = (Hdim * VG) / 4;
    const int n4s = (Hdim * VS) / 4;
    int stride = gridDim.x * blockDim.x;
    for (int i = blockIdx.x * blockDim.x + threadIdx.x; i < n4g + n4s; i += stride) {
        float4 v;
        u64* dst;
        if (i < n4g) { v = ((const float4*)Wg)[i]; dst = (u64*)wgbf + i; }
        else { int j = i - n4g; v = ((const float4*)Ws)[j]; dst = (u64*)wsbf + j; }
        u64 p = (u64)f2bf(v.x) | ((u64)f2bf(v.y) << 16) | ((u64)f2bf(v.z) << 32) | ((u64)f2bf(v.w) << 48);
        *dst = p;
    }
}

// ---------------- h2s -> bf16 (A matrix for GEMM) ----------------
__global__ void k_hbf(const u64* h2x, u16* hbf) {
    int i = blockIdx.x * 256 + threadIdx.x;   // 2048 x 256 == 524288
    hbf[i] = f2bf(upf(ld64(&h2x[i + Hdim]))); // h2s[t] = slot t+1
}

// ---------------- sequential GRU scan: 96 persistent WGs ----------------
#define G1n 32
#define C1n 16
#define G2n 64
#define C2n 8
#define WS 516   // LDS weight column stride (u16): 2-way max aliasing

__launch_bounds__(256)
__global__ void k_scan(const float* Uz1, const float* Ur1, const float* U1,
                       const float* Wz2, const float* Uz2, const float* Wr2,
                       const float* Ur2, const float* W2, const float* U2,
                       const float* xz, const float* xr, const float* x1,
                       u64* h1x, u64* h2x, u64* r1x, u64* r2x) {
    __shared__ u16 wsl[48 * WS];               // 49.5 KB weight slices (bf16)
    __shared__ float hA[2][Hdim], hB[2][Hdim], hC[2][Hdim]; // parity dbuf: no tail barrier
    int tid = threadIdx.x;
    int g = blockIdx.x;

    if (g < G1n) {
        // ---------------- layer 1: 32 WGs x 16 output columns ----------------
        int c0 = g * C1n;
        const float* Us[3] = {Uz1, Ur1, U1};
        for (int m = 0; m < 3; ++m) {
            for (int k = 0; k < 2; ++k) {
                int i = tid + k * 256;
                const float* src = Us[m] + (size_t)i * Hdim + c0;
                float v[16];
#pragma unroll
                for (int q = 0; q < 4; ++q) {
                    float4 f = ((const float4*)src)[q];
                    v[q * 4] = f.x; v[q * 4 + 1] = f.y; v[q * 4 + 2] = f.z; v[q * 4 + 3] = f.w;
                }
#pragma unroll
                for (int cc = 0; cc < 16; ++cc) wsl[(m * C1n + cc) * WS + i] = f2bf(v[cc]);
            }
        }
        __syncthreads();
        int c = tid >> 4, r = tid & 15;
        const u16* wz = &wsl[(0 * C1n + c) * WS];
        const u16* wr = &wsl[(1 * C1n + c) * WS];
        const u16* w1 = &wsl[(2 * C1n + c) * WS];
        for (int t = 0; t < Tlen; ++t) {
            int p = t & 1;
            // prefetch x-projections (only r==0 lanes use them); issued before spin
            float xzv = 0.f, xrv = 0.f, x1v = 0.f;
            if (r == 0) {
                xzv = xz[t * Hdim + c0 + c];
                xrv = xr[t * Hdim + c0 + c];
                x1v = x1[t * Hdim + c0 + c];
            }
            // ---- hop A: per-thread spin on h1x[t] (tag t+1) -> hA[p] ----
            {
                const u64* ph = h1x + (size_t)t * Hdim;
                u32 tg = (u32)(t + 1);
                u64 a0 = spin64(ph + tid, tg);
                u64 a1 = spin64(ph + tid + 256, tg);
                hA[p][tid] = upf(a0); hA[p][tid + 256] = upf(a1);
            }
            __syncthreads();
            // r-gate FIRST: it is the only thing on the inter-WG critical path
            float ar = 0.f;
#pragma unroll 8
            for (int ii = 0; ii < 32; ++ii) {
                int i = r * 32 + ((ii + r) & 31);
                ar += hA[p][i] * bf2f(wr[i]);
            }
#pragma unroll
            for (int d = 8; d; d >>= 1) ar += __shfl_down(ar, d, 16);
            if (r == 0) {
                float rg = sigm(ar + xrv);
                st64(&r1x[(size_t)t * Hdim + c0 + c], pk((u32)(t + 1), rg));
            }
            // z-gate + candidate products: computed in the shadow of hop B
            float az = 0.f;
            float pm[32];
#pragma unroll
            for (int ii = 0; ii < 32; ++ii) {   // FULL unroll: pm[] must stay in regs
                int i = r * 32 + ((ii + r) & 31);
                float h = hA[p][i];
                az += h * bf2f(wz[i]);
                pm[ii] = h * bf2f(w1[i]);
            }
#pragma unroll
            for (int d = 8; d; d >>= 1) az += __shfl_down(az, d, 16);
            float zg = 0.f;
            if (r == 0) zg = sigm(az + xzv);
            // ---- hop B: per-thread spin on r1x[t] -> hB[p] ----
            {
                const u64* pr = r1x + (size_t)t * Hdim;
                u32 tg = (u32)(t + 1);
                u64 a0 = spin64(pr + tid, tg);
                u64 a1 = spin64(pr + tid + 256, tg);
                hB[p][tid] = upf(a0); hB[p][tid + 256] = upf(a1);
            }
            __syncthreads();
            // stage 2: only the r-dependent FMAs remain
            float a = 0.f;
#pragma unroll
            for (int ii = 0; ii < 32; ++ii) {
                int i = r * 32 + ((ii + r) & 31);
                a += hB[p][i] * pm[ii];
            }
#pragma unroll
            for (int d = 8; d; d >>= 1) a += __shfl_down(a, d, 16);
            if (r == 0) {
                float ht = tanhf(a + x1v);
                float hn = zg * ht + (1.f - zg) * hA[p][c0 + c];
                st64(&h1x[(size_t)(t + 1) * Hdim + c0 + c], pk((u32)(t + 2), hn));
            }
            // no tail barrier: hA/hB are parity double-buffered
        }
    } else {
        // ---------------- layer 2: 64 WGs x 8 output columns ----------------
        int g2 = g - G1n, c0 = g2 * C2n;
        const float* Us[6] = {Wz2, Uz2, Wr2, Ur2, W2, U2};
        for (int m = 0; m < 6; ++m) {
            for (int k = 0; k < 2; ++k) {
                int i = tid + k * 256;
                const float* src = Us[m] + (size_t)i * Hdim + c0;
                float v[8];
#pragma unroll
                for (int q = 0; q < 2; ++q) {
                    float4 f = ((const float4*)src)[q];
                    v[q * 4] = f.x; v[q * 4 + 1] = f.y; v[q * 4 + 2] = f.z; v[q * 4 + 3] = f.w;
                }
#pragma unroll
                for (int cc = 0; cc < 8; ++cc) wsl[(m * C2n + cc) * WS + i] = f2bf(v[cc]);
            }
        }
        __syncthreads();
        int c = tid >> 5, r = tid & 31;
        const u16* w0 = &wsl[(0 * C2n + c) * WS];
        const u16* w1p = &wsl[(1 * C2n + c) * WS];
        const u16* w2p = &wsl[(2 * C2n + c) * WS];
        const u16* w3p = &wsl[(3 * C2n + c) * WS];
        const u16* w4p = &wsl[(4 * C2n + c) * WS];
        const u16* w5p = &wsl[(5 * C2n + c) * WS];
        for (int t = 0; t < Tlen; ++t) {
            int p = t & 1;
            // ---- hop A: spin h1x[t+1] (tag t+2) and h2x[t] (tag t+1) ----
            {
                const u64* p1 = h1x + (size_t)(t + 1) * Hdim;
                const u64* p2 = h2x + (size_t)t * Hdim;
                u32 tg1 = (u32)(t + 2), tg2 = (u32)(t + 1);
                u64 a0 = spin64(p1 + tid, tg1);
                u64 a1 = spin64(p1 + tid + 256, tg1);
                u64 b0 = spin64(p2 + tid, tg2);
                u64 b1 = spin64(p2 + tid + 256, tg2);
                hA[p][tid] = upf(a0); hA[p][tid + 256] = upf(a1);
                hB[p][tid] = upf(b0); hB[p][tid + 256] = upf(b1);
            }
            __syncthreads();
            // r2 FIRST (critical path)
            float ar = 0.f;
#pragma unroll 8
            for (int ii = 0; ii < 16; ++ii) {
                int i = r * 16 + ((ii + r) & 15);
                ar += hA[p][i] * bf2f(w2p[i]) + hB[p][i] * bf2f(w3p[i]);
            }
#pragma unroll
            for (int d = 16; d; d >>= 1) ar += __shfl_down(ar, d, 32);
            if (r == 0) {
                st64(&r2x[(size_t)t * Hdim + c0 + c], pk((u32)(t + 1), sigm(ar)));
            }
            // z2 + stage-2 partials in the shadow of hop B
            float az = 0.f, ap = 0.f;
            float pm[16];
#pragma unroll
            for (int ii = 0; ii < 16; ++ii) {   // FULL unroll: pm[] must stay in regs
                int i = r * 16 + ((ii + r) & 15);
                float a_ = hA[p][i], b_ = hB[p][i];
                az += a_ * bf2f(w0[i]) + b_ * bf2f(w1p[i]);
                ap += a_ * bf2f(w4p[i]);
                pm[ii] = b_ * bf2f(w5p[i]);
            }
#pragma unroll
            for (int d = 16; d; d >>= 1) az += __shfl_down(az, d, 32);
            float zg = 0.f;
            if (r == 0) zg = sigm(az);
            // ---- hop B: spin r2x[t] -> hC[p] ----
            {
                const u64* pr = r2x + (size_t)t * Hdim;
                u32 tg = (u32)(t + 1);
                u64 a0 = spin64(pr + tid, tg);
                u64 a1 = spin64(pr + tid + 256, tg);
                hC[p][tid] = upf(a0); hC[p][tid + 256] = upf(a1);
            }
            __syncthreads();
            // stage 2: only the r2-dependent FMAs remain
            float a = ap;
#pragma unroll
            for (int ii = 0; ii < 16; ++ii) {
                int i = r * 16 + ((ii + r) & 15);
                a += hC[p][i] * pm[ii];
            }
#pragma unroll
            for (int d = 16; d; d >>= 1) a += __shfl_down(a, d, 32);
            if (r == 0) {
                float ht = tanhf(a);
                float hn = zg * ht + (1.f - zg) * hB[p][c0 + c];
                st64(&h2x[(size_t)(t + 1) * Hdim + c0 + c], pk((u32)(t + 2), hn));
            }
            // no tail barrier: parity double-buffered
        }
    }
}

// ---------------- bf16 MFMA GEMM: logits + per-block sumexp partials ----------------
typedef __attribute__((ext_vector_type(8))) short bfrag;
typedef __attribute__((ext_vector_type(4))) float f32x4;

__launch_bounds__(256)
__global__ void k_gemm(const u16* A, const u16* B, const float* bias,
                       float* out, float* partial, int N, int nblk) {
    __shared__ u16 As[64 * 40];
    __shared__ u16 Bs[64 * 40];
    int tid = threadIdx.x, lane = tid & 63, wid = tid >> 6;
    int m0 = blockIdx.x * 64, n0 = blockIdx.y * 64;
    f32x4 acc[4] = {{0.f, 0.f, 0.f, 0.f}, {0.f, 0.f, 0.f, 0.f}, {0.f, 0.f, 0.f, 0.f}, {0.f, 0.f, 0.f, 0.f}};
    int arow = tid >> 2, akc = (tid & 3) * 8;
    int bkr = tid >> 3, bnc = (tid & 7) * 8;
    bool bvalid = (n0 + bnc) < N;
    int lm = lane & 15, q = lane >> 4;
    for (int kt = 0; kt < 16; ++kt) {
        int k0 = kt * 32;
        uint4 av = *(const uint4*)(A + (size_t)(m0 + arow) * Hdim + k0 + akc);
        *((uint4*)&As[arow * 40 + akc]) = av;
        union { uint4 v; u16 s[8]; } ub;
        ub.v = make_uint4(0, 0, 0, 0);
        if (bvalid) ub.v = *(const uint4*)(B + (size_t)(k0 + bkr) * N + n0 + bnc);
#pragma unroll
        for (int j = 0; j < 8; ++j) Bs[(bnc + j) * 40 + bkr] = ub.s[j];
        __syncthreads();
        bfrag af = *(const bfrag*)&As[(wid * 16 + lm) * 40 + q * 8];
#pragma unroll
        for (int ns = 0; ns < 4; ++ns) {
            bfrag bf_ = *(const bfrag*)&Bs[(ns * 16 + lm) * 40 + q * 8];
            acc[ns] = __builtin_amdgcn_mfma_f32_16x16x32_bf16(af, bf_, acc[ns], 0, 0, 0);
        }
        __syncthreads();
    }
    float rs[4] = {0.f, 0.f, 0.f, 0.f};
#pragma unroll
    for (int ns = 0; ns < 4; ++ns) {
        int col = n0 + ns * 16 + lm;
        bool cv = col < N;
        float bi = cv ? bias[col] : 0.f;
#pragma unroll
        for (int rr = 0; rr < 4; ++rr) {
            int row = wid * 16 + q * 4 + rr;
            float v = acc[ns][rr] + bi;
            if (cv) {
                out[(size_t)(m0 + row) * N + col] = v;
                rs[rr] += __expf(v);
            }
        }
    }
#pragma unroll
    for (int rr = 0; rr < 4; ++rr) {
#pragma unroll
        for (int d = 1; d < 16; d <<= 1) rs[rr] += __shfl_xor(rs[rr], d, 64);
    }
    if (lm == 0) {
#pragma unroll
        for (int rr = 0; rr < 4; ++rr) {
            int row = wid * 16 + q * 4 + rr;
            partial[(size_t)(m0 + row) * nblk + blockIdx.y] = rs[rr];
        }
    }
}

// ---------------- per-row logsumexp reduce ----------------
__global__ void k_lse(const float* pG, const float* pS, float* lse) {
    int row = blockIdx.x;
    int tid = threadIdx.x;
    const float* p;
    int nb;
    if (row < Tlen) { p = pG + (size_t)row * 625; nb = 625; }
    else { p = pS + (size_t)(row - Tlen) * 391; nb = 391; }
    float s = 0.f;
    for (int j = tid; j < nb; j += 256) s += p[j];
#pragma unroll
    for (int d = 32; d; d >>= 1) s += __shfl_down(s, d, 64);
    __shared__ float red[4];
    if ((tid & 63) == 0) red[tid >> 6] = s;
    __syncthreads();
    if (tid == 0) lse[row] = logf(red[0] + red[1] + red[2] + red[3]);
}

// ---------------- in-place fixup: out -= lse[row] ----------------
__global__ void k_fix(float* out, const float* lse) {
    const size_t n4 = NTOT / 4;
    size_t stride = (size_t)gridDim.x * blockDim.x;
    for (size_t i = (size_t)blockIdx.x * blockDim.x + threadIdx.x; i < n4; i += stride) {
        size_t e = i * 4;
        float l;
        if (e < (size_t)NGTOT) l = lse[e / VG];
        else l = lse[Tlen + (e - (size_t)NGTOT) / VS];
        float4 v = ((float4*)out)[i];
        v.x -= l; v.y -= l; v.z -= l; v.w -= l;
        ((float4*)out)[i] = v;
    }
}

extern "C" void kernel_launch(void* const* d_in, const int* in_sizes, int n_in,
                              void* d_out, int out_size, void* d_ws, size_t ws_size,
                              hipStream_t stream) {
    const int* tokens = (const int*)d_in[0];
    const float* X   = (const float*)d_in[1];
    const float* Wz1 = (const float*)d_in[2];
    const float* Uz1 = (const float*)d_in[3];
    const float* Wr1 = (const float*)d_in[4];
    const float* Ur1 = (const float*)d_in[5];
    const float* W1  = (const float*)d_in[6];
    const float* U1  = (const float*)d_in[7];
    const float* Wz2 = (const float*)d_in[8];
    const float* Uz2 = (const float*)d_in[9];
    const float* Wr2 = (const float*)d_in[10];
    const float* Ur2 = (const float*)d_in[11];
    const float* W2  = (const float*)d_in[12];
    const float* U2  = (const float*)d_in[13];
    const float* Wg  = (const float*)d_in[14];
    const float* bg  = (const float*)d_in[15];
    const float* Ws  = (const float*)d_in[16];
    const float* bs  = (const float*)d_in[17];

    float* wsf = (float*)d_ws;
    float* xz = wsf + F_XZ;
    float* xr = wsf + F_XR;
    float* x1 = wsf + F_X1;
    u64* h1x = (u64*)(wsf + F_H1X);
    u64* h2x = (u64*)(wsf + F_H2X);
    u64* r1x = (u64*)(wsf + F_R1X);
    u64* r2x = (u64*)(wsf + F_R2X);
    u16* hbf  = (u16*)(wsf + F_HBF);
    u16* wgbf = (u16*)(wsf + F_WGBF);
    u16* wsbf = (u16*)(wsf + F_WSBF);
    float* pG = wsf + F_PG;
    float* pS = wsf + F_PS;
    float* lse = wsf + F_LSE;
    float* outF = (float*)d_out;

    hipLaunchKernelGGL(k_init, dim3(2), dim3(256), 0, stream, h1x, h2x);
    hipLaunchKernelGGL(k_xproj, dim3(64, 24), dim3(256), 0, stream,
                       tokens, X, Wz1, Wr1, W1, xz, xr, x1);
    hipLaunchKernelGGL(k_wconv, dim3(4096), dim3(256), 0, stream, Wg, Ws, wgbf, wsbf);
    hipLaunchKernelGGL(k_scan, dim3(96), dim3(256), 0, stream,
                       Uz1, Ur1, U1, Wz2, Uz2, Wr2, Ur2, W2, U2,
                       xz, xr, x1, h1x, h2x, r1x, r2x);
    hipLaunchKernelGGL(k_hbf, dim3(2048), dim3(256), 0, stream, h2x, hbf);
    hipLaunchKernelGGL(k_gemm, dim3(16, 625), dim3(256), 0, stream,
                       hbf, wgbf, bg, outF, pG, VG, 625);
    hipLaunchKernelGGL(k_gemm, dim3(16, 391), dim3(256), 0, stream,
                       hbf, wsbf, bs, outF + (size_t)NGTOT, pS, VS, 391);
    hipLaunchKernelGGL(k_lse, dim3(2048), dim3(256), 0, stream, pG, pS, lse);
    hipLaunchKernelGGL(k_fix, dim3(8192), dim3(256), 0, stream, outF, lse);
}